// Round 1
// baseline (821.444 us; speedup 1.0000x reference)
//
#include <hip/hip_runtime.h>
#include <math.h>

// GeodesicAttention: B=4, T=2048, D=1024, R=32
//   y = x @ U            [B,T,R]
//   n[t] = ||y_t||^2
//   logits[t,j] = 2*y_t.y_j - n_j   (row-constant -n_t cancels in softmax)
//   out = softmax(logits) @ x
#define B_ 4
#define T_ 2048
#define D_ 1024
#define R_ 32

#define TQ 32    // q rows per block
#define TK 64    // k rows per tile
#define DC 128   // output columns per block
#define SP 36    // padded LDS stride (36*4B = 144B, multiple of 16B; breaks pow2 banks)

// ---------------- Kernel 1: y = x U, n = rowsum(y^2) ----------------
// block = 256 = 8 rows x 32 r-lanes. x row read broadcast across 32 lanes,
// U reads coalesced 32-wide.
__global__ __launch_bounds__(256)
void geo_y_kernel(const float* __restrict__ x, const float* __restrict__ U,
                  float* __restrict__ y, float* __restrict__ nsq) {
  const int tid = threadIdx.x;
  const int rl  = tid >> 5;      // row within block
  const int r   = tid & 31;      // which of 32 metric dims
  const size_t row = (size_t)blockIdx.x * 8 + rl;   // flattened b*T + t
  const float4* x4 = (const float4*)(x + row * D_);
  float acc = 0.f;
  #pragma unroll 8
  for (int d4 = 0; d4 < D_ / 4; d4++) {
    float4 xv = x4[d4];
    int d = d4 * 4;
    acc += xv.x * U[(d + 0) * R_ + r];
    acc += xv.y * U[(d + 1) * R_ + r];
    acc += xv.z * U[(d + 2) * R_ + r];
    acc += xv.w * U[(d + 3) * R_ + r];
  }
  y[row * R_ + r] = acc;
  float a2 = acc * acc;
  // sum across the 32 lanes of this row (xor masks <32 stay within the half-wave)
  #pragma unroll
  for (int off = 16; off >= 1; off >>= 1)
    a2 += __shfl_xor(a2, off, 64);
  if (r == 0) nsq[row] = a2;
}

// ---------------- Kernel 2: flash-style streaming softmax-attention ----------------
// grid.x = (T/TQ) * (D/DC), grid.y = B. block = 256 threads.
// Score phase:  srow = tid>>3 (one q-row per thread, yq cached in regs),
//               sub = tid&7, jj = sub + 8*i (keeps LDS banks spread).
// PV phase:     rg = tid>>5 -> rows rg*4..rg*4+3, cl = tid&31 -> cols c0..c0+3,
//               4x4 register tile, x loads coalesced float4 from global.
__global__ __launch_bounds__(256)
void geo_attn_kernel(const float* __restrict__ x, const float* __restrict__ y,
                     const float* __restrict__ nsq, float* __restrict__ out) {
  const int b   = blockIdx.y;
  const int qt  = blockIdx.x / (D_ / DC);
  const int dc  = blockIdx.x % (D_ / DC);
  const int q0  = qt * TQ;
  const int tid = threadIdx.x;
  const int sub  = tid & 7;
  const int srow = tid >> 3;
  const int cl   = tid & 31;
  const int rg   = tid >> 5;

  __shared__ float Yj[TK][SP];     // k-tile of y
  __shared__ float Pt[TK][SP];     // scores, then probabilities, transposed [jj][row]
  __shared__ float njS[TK];
  __shared__ float mS[TQ], lS[TQ], alphaS[TQ];
  __shared__ float red[8][TQ];     // partial max / partial sum

  // register-cache this thread's q row of y
  float yq[R_];
  {
    const float* yr = y + ((size_t)(b * T_) + q0 + srow) * R_;
    #pragma unroll
    for (int r = 0; r < R_; r += 4) {
      float4 v = *(const float4*)(yr + r);
      yq[r] = v.x; yq[r + 1] = v.y; yq[r + 2] = v.z; yq[r + 3] = v.w;
    }
  }
  if (tid < TQ) { mS[tid] = -1e30f; lS[tid] = 0.f; }

  float acc[4][4];
  #pragma unroll
  for (int i = 0; i < 4; i++)
    #pragma unroll
    for (int j = 0; j < 4; j++) acc[i][j] = 0.f;

  const int c0 = dc * DC + cl * 4;
  const float* xb = x + (size_t)b * T_ * D_;
  const float* yb = y + (size_t)b * T_ * R_;
  const float* nb = nsq + b * T_;
  float* ob = out + (size_t)b * T_ * D_;

  for (int j0 = 0; j0 < T_; j0 += TK) {
    __syncthreads();   // previous tile's PV done before Yj/njS overwritten
    // ---- stage Yj (64x32) + nj ----
    {
      int e  = tid * 8;           // 2048 elements, 8 per thread, coalesced
      int jj = e >> 5, r0 = e & 31;
      const float* src = yb + (size_t)j0 * R_ + e;
      float4 v0 = *(const float4*)(src);
      float4 v1 = *(const float4*)(src + 4);
      *(float4*)&Yj[jj][r0]     = v0;
      *(float4*)&Yj[jj][r0 + 4] = v1;
      if (tid < TK) njS[tid] = nb[j0 + tid];
    }
    __syncthreads();
    // ---- scores: Pt[jj][srow] = 2*yq.yj - n_j ----
    #pragma unroll
    for (int i = 0; i < 8; i++) {
      int jj = sub + 8 * i;
      float s = 0.f;
      #pragma unroll
      for (int r = 0; r < R_; r += 4) {
        float4 v = *(const float4*)&Yj[jj][r];
        s += yq[r] * v.x + yq[r + 1] * v.y + yq[r + 2] * v.z + yq[r + 3] * v.w;
      }
      Pt[jj][srow] = 2.f * s - njS[jj];
    }
    __syncthreads();
    // ---- online softmax: partial max ----
    {
      int row = tid & 31, ch = tid >> 5;
      float pm = -1e30f;
      #pragma unroll
      for (int i = 0; i < 8; i++) pm = fmaxf(pm, Pt[ch * 8 + i][row]);
      red[ch][row] = pm;
    }
    __syncthreads();
    if (tid < TQ) {
      float tm = red[0][tid];
      #pragma unroll
      for (int ch = 1; ch < 8; ch++) tm = fmaxf(tm, red[ch][tid]);
      float mo = mS[tid];
      float mn = fmaxf(mo, tm);
      float al = __expf(mo - mn);   // first tile: exp(-1e30)=0, no NaN
      mS[tid] = mn; alphaS[tid] = al;
      lS[tid] *= al;
    }
    __syncthreads();
    // ---- exponentiate + partial sums ----
    {
      int row = tid & 31, ch = tid >> 5;
      float mn = mS[row];
      float ps = 0.f;
      #pragma unroll
      for (int i = 0; i < 8; i++) {
        float p = __expf(Pt[ch * 8 + i][row] - mn);
        Pt[ch * 8 + i][row] = p;
        ps += p;
      }
      red[ch][row] = ps;
    }
    __syncthreads();
    if (tid < TQ) {
      float s = 0.f;
      #pragma unroll
      for (int ch = 0; ch < 8; ch++) s += red[ch][tid];
      lS[tid] += s;   // no barrier needed before PV (PV reads alphaS/Pt only)
    }
    // ---- PV: acc = acc*alpha + P x ----
    float al0 = alphaS[rg * 4 + 0], al1 = alphaS[rg * 4 + 1];
    float al2 = alphaS[rg * 4 + 2], al3 = alphaS[rg * 4 + 3];
    #pragma unroll
    for (int j = 0; j < 4; j++) {
      acc[0][j] *= al0; acc[1][j] *= al1; acc[2][j] *= al2; acc[3][j] *= al3;
    }
    #pragma unroll 4
    for (int jj = 0; jj < TK; jj++) {
      float4 xv = *(const float4*)(xb + (size_t)(j0 + jj) * D_ + c0);
      float4 pv = *(const float4*)&Pt[jj][rg * 4];   // broadcast across cl lanes
      acc[0][0] += pv.x * xv.x; acc[0][1] += pv.x * xv.y; acc[0][2] += pv.x * xv.z; acc[0][3] += pv.x * xv.w;
      acc[1][0] += pv.y * xv.x; acc[1][1] += pv.y * xv.y; acc[1][2] += pv.y * xv.z; acc[1][3] += pv.y * xv.w;
      acc[2][0] += pv.z * xv.x; acc[2][1] += pv.z * xv.y; acc[2][2] += pv.z * xv.z; acc[2][3] += pv.z * xv.w;
      acc[3][0] += pv.w * xv.x; acc[3][1] += pv.w * xv.y; acc[3][2] += pv.w * xv.z; acc[3][3] += pv.w * xv.w;
    }
  }
  __syncthreads();  // lS final
  float inv0 = 1.f / lS[rg * 4 + 0], inv1 = 1.f / lS[rg * 4 + 1];
  float inv2 = 1.f / lS[rg * 4 + 2], inv3 = 1.f / lS[rg * 4 + 3];
  float invs[4] = {inv0, inv1, inv2, inv3};
  #pragma unroll
  for (int rr = 0; rr < 4; rr++) {
    float4 o;
    o.x = acc[rr][0] * invs[rr]; o.y = acc[rr][1] * invs[rr];
    o.z = acc[rr][2] * invs[rr]; o.w = acc[rr][3] * invs[rr];
    *(float4*)(ob + (size_t)(q0 + rg * 4 + rr) * D_ + c0) = o;
  }
}

extern "C" void kernel_launch(void* const* d_in, const int* in_sizes, int n_in,
                              void* d_out, int out_size, void* d_ws, size_t ws_size,
                              hipStream_t stream) {
  const float* x = (const float*)d_in[0];
  const float* U = (const float*)d_in[1];
  float* out = (float*)d_out;
  float* y   = (float*)d_ws;                       // B*T*R floats = 1 MB
  float* nsq = y + (size_t)B_ * T_ * R_;           // B*T floats
  hipLaunchKernelGGL(geo_y_kernel, dim3(B_ * T_ / 8), dim3(256), 0, stream,
                     x, U, y, nsq);
  hipLaunchKernelGGL(geo_attn_kernel, dim3((T_ / TQ) * (D_ / DC), B_), dim3(256), 0, stream,
                     x, y, nsq, out);
}

// Round 2
// 288.805 us; speedup vs baseline: 2.8443x; 2.8443x over previous
//
#include <hip/hip_runtime.h>
#include <math.h>

// GeodesicAttention: B=4, T=2048, D=1024, R=32
//   y = x @ U; logits[t,j] = 2*y_t.y_j - ||y_j||^2 (row-const -||y_t||^2 cancels)
//   out = softmax(logits) @ x
// Round 2: bf16 MFMA flash attention.
//   prep: ybf = bf16(sqrt2 * y)  (folds the 2x into the MFMA), nsq fp32,
//         xt[b][d][t] = bf16(x) pretransposed so PV B-frags are k-contiguous.
//   attn: TQ=64 q-rows, DC=128 d-cols, TK=64 k-tile, 4 waves.
//         wave w owns q-rows [w*16,w*16+16) for QK^T+softmax (intra-quad
//         shuffle reductions only), all 64 q x its 32 d-cols for PV.
#define B_ 4
#define T_ 2048
#define D_ 1024
#define R_ 32

#define TQ 64
#define TK 64
#define DC 128
#define PSTR 72   // Pbuf row stride in shorts (144B: 16B-aligned, 2-way banks max)

typedef __attribute__((ext_vector_type(8))) short short8;
typedef __attribute__((ext_vector_type(4))) float f32x4;

__device__ __forceinline__ unsigned short f2bf(float f) {
  union { float f; unsigned u; } v; v.f = f;
  unsigned r = (v.u + 0x7fffu + ((v.u >> 16) & 1u)) >> 16;
  return (unsigned short)r;
}

// ---------------- Kernel 1: y = x U; nsq = ||y||^2; ybf = bf16(sqrt2*y) --------
__global__ __launch_bounds__(256)
void geo_y(const float* __restrict__ x, const float* __restrict__ U,
           unsigned short* __restrict__ ybf, float* __restrict__ nsq) {
  const int tid = threadIdx.x;
  const int rl  = tid >> 5;
  const int r   = tid & 31;
  const size_t row = (size_t)blockIdx.x * 8 + rl;
  const float4* x4 = (const float4*)(x + row * D_);
  float acc = 0.f;
  #pragma unroll 8
  for (int d4 = 0; d4 < D_ / 4; d4++) {
    float4 xv = x4[d4];
    int d = d4 * 4;
    acc += xv.x * U[(d + 0) * R_ + r];
    acc += xv.y * U[(d + 1) * R_ + r];
    acc += xv.z * U[(d + 2) * R_ + r];
    acc += xv.w * U[(d + 3) * R_ + r];
  }
  ybf[row * R_ + r] = f2bf(acc * 1.41421356237f);
  float a2 = acc * acc;
  #pragma unroll
  for (int off = 16; off >= 1; off >>= 1)
    a2 += __shfl_xor(a2, off, 64);
  if (r == 0) nsq[row] = a2;
}

// ---------------- Kernel 2: xt[b][d][t] = bf16(x[b][t][d]) ----------------
__global__ __launch_bounds__(256)
void geo_xt(const float* __restrict__ x, unsigned short* __restrict__ xt) {
  __shared__ float tile[32][33];
  const int tx = threadIdx.x & 31, ty = threadIdx.x >> 5;
  const int b = blockIdx.z;
  const int t0 = blockIdx.y * 32, d0 = blockIdx.x * 32;
  const float* xb = x + ((size_t)b * T_ + t0) * D_ + d0;
  #pragma unroll
  for (int i = 0; i < 4; i++)
    tile[ty + i * 8][tx] = xb[(size_t)(ty + i * 8) * D_ + tx];
  __syncthreads();
  unsigned short* xo = xt + ((size_t)b * D_ + d0) * T_ + t0;
  #pragma unroll
  for (int i = 0; i < 4; i++) {
    int d = ty + i * 8;
    xo[(size_t)d * T_ + tx] = f2bf(tile[tx][d]);
  }
}

// ---------------- Kernel 3: flash attention, bf16 MFMA ----------------
__global__ __launch_bounds__(256)
void geo_attn(const unsigned short* __restrict__ ybf,
              const float* __restrict__ nsq,
              const unsigned short* __restrict__ xt,
              float* __restrict__ out) {
  const int b  = blockIdx.y;
  const int qt = blockIdx.x / (D_ / DC);
  const int dc = blockIdx.x % (D_ / DC);
  const int q0 = qt * TQ;
  const int d0 = dc * DC;
  const int tid  = threadIdx.x;
  const int w    = tid >> 6;
  const int lane = tid & 63;
  const int m    = lane & 15;
  const int quad = lane >> 4;

  // X^T tile: chunk = 8 d-rows x 64 k (1 KB). Within a chunk, 16B slot
  // (dl, sl) holds k-slot (sl^dl) of d-row dl — XOR swizzle chosen at the
  // GLOBAL address so global_load_lds's fixed lane->LDS mapping still gives
  // <=2-way bank access on B-frag ds_read_b128.
  __shared__ unsigned short XtS[DC * TK];      // 16 KB
  __shared__ unsigned short Pbuf[TQ * PSTR];   // 9.2 KB, P in A-layout rows
  __shared__ float alphaS[TQ];
  __shared__ float lS[TQ];

  const size_t yb = (size_t)b * T_ * R_;
  const size_t nb = (size_t)b * T_;
  // A-frag of Yq for this wave's 16 q-rows (K=32 covers all of R)
  short8 aq = *(const short8*)(ybf + yb + (size_t)(q0 + w * 16 + m) * R_ + quad * 8);

  f32x4 acc[4][2];
  #pragma unroll
  for (int s = 0; s < 4; s++)
    #pragma unroll
    for (int nt = 0; nt < 2; nt++)
      acc[s][nt] = (f32x4){0.f, 0.f, 0.f, 0.f};

  float mrow[4] = {-1e30f, -1e30f, -1e30f, -1e30f};
  float lrow[4] = {0.f, 0.f, 0.f, 0.f};

  const unsigned short* xtb = xt + ((size_t)b * D_ + d0) * T_;
  const int sdl = lane >> 3, ssl = lane & 7;
  const int wks = ssl ^ sdl;                 // k-slot this lane fetches

  for (int j0 = 0; j0 < T_; j0 += TK) {
    __syncthreads();   // prior PV done: safe to overwrite XtS/Pbuf/alphaS
    // ---- stage X^T tile: wave w stages chunks 4w..4w+3 ----
    #pragma unroll
    for (int cc = 0; cc < 4; cc++) {
      int chunk = w * 4 + cc;
      int d = chunk * 8 + sdl;
      const unsigned short* g = xtb + (size_t)d * T_ + j0 + wks * 8;
      __builtin_amdgcn_global_load_lds(
          (const __attribute__((address_space(1))) void*)g,
          (__attribute__((address_space(3))) void*)(XtS + chunk * 512),
          16, 0, 0);
    }
    // ---- QK^T for this wave's 16 q rows x 64 k cols ----
    f32x4 sc[4];
    #pragma unroll
    for (int nt = 0; nt < 4; nt++) {
      short8 bk = *(const short8*)(ybf + yb + (size_t)(j0 + nt * 16 + m) * R_ + quad * 8);
      f32x4 z = {0.f, 0.f, 0.f, 0.f};
      sc[nt] = __builtin_amdgcn_mfma_f32_16x16x32_bf16(aq, bk, z, 0, 0, 0);
      float nj = nsq[nb + j0 + nt * 16 + m];   // C col = lane&15 = this k col
      #pragma unroll
      for (int r = 0; r < 4; r++) sc[nt][r] -= nj;
    }
    // ---- online softmax (rows = quad*4+r, mates = 16 lanes of this quad) ----
    float tmax[4];
    #pragma unroll
    for (int r = 0; r < 4; r++)
      tmax[r] = fmaxf(fmaxf(sc[0][r], sc[1][r]), fmaxf(sc[2][r], sc[3][r]));
    #pragma unroll
    for (int off = 1; off < 16; off <<= 1)
      #pragma unroll
      for (int r = 0; r < 4; r++)
        tmax[r] = fmaxf(tmax[r], __shfl_xor(tmax[r], off, 64));
    float alpha[4], psum[4];
    #pragma unroll
    for (int r = 0; r < 4; r++) {
      float mn = fmaxf(mrow[r], tmax[r]);
      alpha[r] = __expf(mrow[r] - mn);   // first tile: expf(-1e30)=0
      mrow[r] = mn;
      psum[r] = 0.f;
    }
    #pragma unroll
    for (int nt = 0; nt < 4; nt++)
      #pragma unroll
      for (int r = 0; r < 4; r++) {
        float p = __expf(sc[nt][r] - mrow[r]);
        psum[r] += p;
        Pbuf[(w * 16 + quad * 4 + r) * PSTR + nt * 16 + m] = f2bf(p);
      }
    #pragma unroll
    for (int off = 1; off < 16; off <<= 1)
      #pragma unroll
      for (int r = 0; r < 4; r++)
        psum[r] += __shfl_xor(psum[r], off, 64);
    #pragma unroll
    for (int r = 0; r < 4; r++) lrow[r] = lrow[r] * alpha[r] + psum[r];
    if (m == 0) {
      f32x4 av = {alpha[0], alpha[1], alpha[2], alpha[3]};
      *(f32x4*)&alphaS[w * 16 + quad * 4] = av;
    }
    __syncthreads();   // XtS staged (vmcnt drained), Pbuf/alphaS visible
    // ---- PV: acc[s][nt] = acc*alpha + P[s-th 16q][64k] @ X[64k][nt-th 16d] ----
    short8 bx[2][2];
    #pragma unroll
    for (int nt = 0; nt < 2; nt++) {
      int dloc = w * 32 + nt * 16 + m;
      int xdl = dloc & 7, ch = dloc >> 3;
      #pragma unroll
      for (int t = 0; t < 2; t++) {
        int ks = t * 4 + quad;
        bx[nt][t] = *(const short8*)(XtS + ch * 512 + (xdl * 8 + (ks ^ xdl)) * 8);
      }
    }
    #pragma unroll
    for (int s = 0; s < 4; s++) {
      f32x4 av = *(const f32x4*)&alphaS[s * 16 + quad * 4];
      short8 a0 = *(const short8*)&Pbuf[(s * 16 + m) * PSTR + quad * 8];
      short8 a1 = *(const short8*)&Pbuf[(s * 16 + m) * PSTR + 32 + quad * 8];
      #pragma unroll
      for (int nt = 0; nt < 2; nt++) {
        f32x4 a = acc[s][nt];
        #pragma unroll
        for (int r = 0; r < 4; r++) a[r] *= av[r];
        a = __builtin_amdgcn_mfma_f32_16x16x32_bf16(a0, bx[nt][0], a, 0, 0, 0);
        a = __builtin_amdgcn_mfma_f32_16x16x32_bf16(a1, bx[nt][1], a, 0, 0, 0);
        acc[s][nt] = a;
      }
    }
  }
  if (m == 0) {
    f32x4 lv = {lrow[0], lrow[1], lrow[2], lrow[3]};
    *(f32x4*)&lS[w * 16 + quad * 4] = lv;
  }
  __syncthreads();
  float* ob = out + ((size_t)b * T_ + q0) * D_ + d0;
  #pragma unroll
  for (int s = 0; s < 4; s++) {
    f32x4 lv = *(const f32x4*)&lS[s * 16 + quad * 4];
    f32x4 inv;
    #pragma unroll
    for (int r = 0; r < 4; r++) inv[r] = 1.f / lv[r];
    #pragma unroll
    for (int nt = 0; nt < 2; nt++)
      #pragma unroll
      for (int r = 0; r < 4; r++)
        ob[(size_t)(s * 16 + quad * 4 + r) * D_ + w * 32 + nt * 16 + m] =
            acc[s][nt][r] * inv[r];
  }
}

extern "C" void kernel_launch(void* const* d_in, const int* in_sizes, int n_in,
                              void* d_out, int out_size, void* d_ws, size_t ws_size,
                              hipStream_t stream) {
  const float* x = (const float*)d_in[0];
  const float* U = (const float*)d_in[1];
  float* out = (float*)d_out;
  // ws: xt (B*D*T bf16 = 16 MB) | ybf (B*T*R bf16 = 512 KB) | nsq (B*T f32)
  unsigned short* xtp = (unsigned short*)d_ws;
  unsigned short* ybf = xtp + (size_t)B_ * D_ * T_;
  float* nsq = (float*)(ybf + (size_t)B_ * T_ * R_);
  hipLaunchKernelGGL(geo_y, dim3(B_ * T_ / 8), dim3(256), 0, stream, x, U, ybf, nsq);
  hipLaunchKernelGGL(geo_xt, dim3(D_ / 32, T_ / 32, B_), dim3(256), 0, stream, x, xtp);
  hipLaunchKernelGGL(geo_attn, dim3((T_ / TQ) * (D_ / DC), B_), dim3(256), 0, stream,
                     ybf, nsq, xtp, out);
}

// Round 3
// 208.014 us; speedup vs baseline: 3.9490x; 1.3884x over previous
//
#include <hip/hip_runtime.h>

// GeodesicAttention: B=4, T=2048, D=1024, R=32
//   y = x @ U; logits[t,j] = 2 y_t.y_j - n_j  (row-const -n_t cancels)
//   KEY: max_j logit = n_t exactly (2ab - b^2 <= a^2, equality j=t), so
//   p[t,j] = exp(2 y_t.y_j - n_j - n_t) in (0,1] with NO online max/rescale.
// Pipeline:
//   geo_y      : ybf = bf16(sqrt2*y), nsq fp32, zero l
//   geo_xt     : xt[b][d][t] = bf16(x)   (B^T form for the PV GEMM)
//   geo_scores : P[b][t][jloc] = bf16(p), l[b][t] += rowsum (atomic)
//   geo_pv     : out = (P @ xt^T) / l    (m97-style 128x128 bf16 GEMM)
// P is slabbed over j if ws_size is small (nslab chosen from ws_size; constant
// across calls -> graph-capture safe).
#define B_ 4
#define T_ 2048
#define D_ 1024
#define R_ 32

typedef __attribute__((ext_vector_type(8))) short short8;
typedef __attribute__((ext_vector_type(4))) float f32x4;
typedef __attribute__((ext_vector_type(4))) unsigned short us4;
typedef __attribute__((ext_vector_type(8))) unsigned short us8;

__device__ __forceinline__ unsigned short f2bf(float f) {
  union { float f; unsigned u; } v; v.f = f;
  unsigned r = (v.u + 0x7fffu + ((v.u >> 16) & 1u)) >> 16;
  return (unsigned short)r;
}

// ---------------- y = x U; ybf = bf16(sqrt2*y); nsq = |y|^2; l = 0 ----------
__global__ __launch_bounds__(256)
void geo_y(const float* __restrict__ x, const float* __restrict__ U,
           unsigned short* __restrict__ ybf, float* __restrict__ nsq,
           float* __restrict__ l) {
  const int tid = threadIdx.x;
  const int rl  = tid >> 5;
  const int r   = tid & 31;
  const size_t row = (size_t)blockIdx.x * 8 + rl;
  const float4* x4 = (const float4*)(x + row * D_);
  float acc = 0.f;
  #pragma unroll 8
  for (int d4 = 0; d4 < D_ / 4; d4++) {
    float4 xv = x4[d4];
    int d = d4 * 4;
    acc += xv.x * U[(d + 0) * R_ + r];
    acc += xv.y * U[(d + 1) * R_ + r];
    acc += xv.z * U[(d + 2) * R_ + r];
    acc += xv.w * U[(d + 3) * R_ + r];
  }
  ybf[row * R_ + r] = f2bf(acc * 1.41421356237f);
  float a2 = acc * acc;
  #pragma unroll
  for (int off = 16; off >= 1; off >>= 1)
    a2 += __shfl_xor(a2, off, 64);
  if (r == 0) { nsq[row] = a2; l[row] = 0.f; }
}

// ---------------- xt[b][d][t] = bf16(x[b][t][d]), 16B packed stores ---------
__global__ __launch_bounds__(256)
void geo_xt(const float* __restrict__ x, unsigned short* __restrict__ xt) {
  __shared__ float tile[64][65];
  const int tid = threadIdx.x;
  const int b = blockIdx.z;
  const int t0 = blockIdx.x * 64, d0 = blockIdx.y * 64;
  {
    const int lr = tid >> 2;              // t-row 0..63
    const int c0 = (tid & 3) * 16;        // 16 d-cols per thread
    const float* xb = x + ((size_t)b * T_ + t0 + lr) * D_ + d0 + c0;
    #pragma unroll
    for (int i = 0; i < 4; i++) {
      float4 v = *(const float4*)(xb + i * 4);
      *(float4*)&tile[lr][c0 + i * 4] = v;
    }
  }
  __syncthreads();
  const int seg = tid & 7;                // 8 t-cols per store
  #pragma unroll
  for (int h = 0; h < 2; h++) {
    int d = h * 32 + (tid >> 3);
    us8 o;
    #pragma unroll
    for (int k2 = 0; k2 < 8; k2++) o[k2] = f2bf(tile[seg * 8 + k2][d]);
    *(us8*)(xt + ((size_t)b * D_ + d0 + d) * T_ + t0 + seg * 8) = o;
  }
}

// ---------------- P[b][t][jloc] = bf16(exp(2yy - nj - nt)); l += rowsum -----
// block tile: 128 j x 128 t; wave w owns j-rows [w*32, w*32+32).
// MFMA A = Yj (rows=j), B = Yt (cols=t): C col=lane&15 -> t, row=quad*4+r -> j.
// Store packs the lane's 4 contiguous j values into one 8B write.
__global__ __launch_bounds__(256)
void geo_scores(const unsigned short* __restrict__ ybf,
                const float* __restrict__ nsq,
                unsigned short* __restrict__ P, float* __restrict__ l,
                int jg0, int Kslab) {
  const int b = blockIdx.z;
  const int t0 = blockIdx.x * 128;
  const int jl0 = blockIdx.y * 128;
  const int tid = threadIdx.x, w = tid >> 6, lane = tid & 63;
  const int m = lane & 15, quad = lane >> 4;
  const unsigned short* yb = ybf + (size_t)b * T_ * R_;
  const float* nb = nsq + b * T_;
  const int jw = jl0 + w * 32;
  short8 aj[2]; f32x4 njv[2];
  #pragma unroll
  for (int rb = 0; rb < 2; rb++) {
    aj[rb] = *(const short8*)(yb + (size_t)(jg0 + jw + rb * 16 + m) * R_ + quad * 8);
    njv[rb] = *(const f32x4*)(nb + jg0 + jw + rb * 16 + quad * 4);
  }
  unsigned short* Pb = P + (size_t)b * T_ * Kslab;
  #pragma unroll 2
  for (int cb = 0; cb < 8; cb++) {
    const int t = t0 + cb * 16 + m;
    short8 bt = *(const short8*)(yb + (size_t)t * R_ + quad * 8);
    float nt = nb[t];
    float ls = 0.f;
    #pragma unroll
    for (int rb = 0; rb < 2; rb++) {
      f32x4 z = {0.f, 0.f, 0.f, 0.f};
      f32x4 c = __builtin_amdgcn_mfma_f32_16x16x32_bf16(aj[rb], bt, z, 0, 0, 0);
      us4 pk;
      #pragma unroll
      for (int r = 0; r < 4; r++) {
        float p = __expf(c[r] - njv[rb][r] - nt);
        ls += p;
        pk[r] = f2bf(p);
      }
      *(us4*)(Pb + (size_t)t * Kslab + jw + rb * 16 + quad * 4) = pk;
    }
    ls += __shfl_xor(ls, 16, 64);
    ls += __shfl_xor(ls, 32, 64);
    if (quad == 0) atomicAdd(&l[b * T_ + t], ls);
  }
}

// ---------------- out = (P @ xt^T) / l  (m97-style 128x128, BK=64) ----------
// grid.x = 128 = 16 t-tiles x 8 d-tiles, XCD-swizzled: the 8 d-tiles sharing a
// P row-tile get ids with equal (id&7) -> same XCD's L2 (perf-only heuristic).
__global__ __launch_bounds__(256)
void geo_pv(const unsigned short* __restrict__ P,
            const unsigned short* __restrict__ xt,
            const float* __restrict__ l, float* __restrict__ out,
            int Kslab, int kxt0, int accumulate, int normalize) {
  __shared__ unsigned short As[128 * 64];   // P tile, [row][slot^row] swizzled
  __shared__ unsigned short Bs[128 * 64];   // xt tile, same swizzle
  const int b = blockIdx.z;
  const int id = blockIdx.x;
  const int cls = id & 7, kk = id >> 3;
  const int t0 = (2 * cls + (kk >> 3)) * 128;
  const int d0 = (kk & 7) * 128;
  const int tid = threadIdx.x, w = tid >> 6, lane = tid & 63;
  const int m = lane & 15, quad = lane >> 4;
  const int wr = (w & 1) * 64, wc = (w >> 1) * 64;
  const int srow = lane >> 3, sslot = lane & 7;
  const unsigned short* Pb = P + ((size_t)b * T_ + t0) * Kslab;
  const unsigned short* Xb = xt + ((size_t)b * D_ + d0) * T_ + kxt0;
  f32x4 acc[4][4];
  #pragma unroll
  for (int i = 0; i < 4; i++)
    #pragma unroll
    for (int j = 0; j < 4; j++) acc[i][j] = (f32x4){0.f, 0.f, 0.f, 0.f};

  for (int k0 = 0; k0 < Kslab; k0 += 64) {
    __syncthreads();
    #pragma unroll
    for (int cc = 0; cc < 4; cc++) {
      const int row = w * 32 + cc * 8 + srow;       // lane's global source row
      const int gs = sslot ^ (row & 7);             // XOR-swizzled k-slot
      __builtin_amdgcn_global_load_lds(
          (const __attribute__((address_space(1))) void*)(Pb + (size_t)row * Kslab + k0 + gs * 8),
          (__attribute__((address_space(3))) void*)(As + (w * 32 + cc * 8) * 64),
          16, 0, 0);
      __builtin_amdgcn_global_load_lds(
          (const __attribute__((address_space(1))) void*)(Xb + (size_t)row * T_ + k0 + gs * 8),
          (__attribute__((address_space(3))) void*)(Bs + (w * 32 + cc * 8) * 64),
          16, 0, 0);
    }
    __syncthreads();
    #pragma unroll
    for (int ks = 0; ks < 2; ks++) {
      short8 af[4], bf[4];
      #pragma unroll
      for (int i = 0; i < 4; i++) {
        const int ra = wr + i * 16 + m;
        af[i] = *(const short8*)(As + ra * 64 + (((ks * 4 + quad) ^ (m & 7)) * 8));
        const int cd = wc + i * 16 + m;
        bf[i] = *(const short8*)(Bs + cd * 64 + (((ks * 4 + quad) ^ (m & 7)) * 8));
      }
      #pragma unroll
      for (int rb = 0; rb < 4; rb++)
        #pragma unroll
        for (int cb = 0; cb < 4; cb++)
          acc[rb][cb] = __builtin_amdgcn_mfma_f32_16x16x32_bf16(af[rb], bf[cb], acc[rb][cb], 0, 0, 0);
    }
  }
  float* ob = out + ((size_t)b * T_ + t0 + wr) * D_ + d0 + wc;
  #pragma unroll
  for (int rb = 0; rb < 4; rb++) {
    f32x4 lv = *(const f32x4*)(l + b * T_ + t0 + wr + rb * 16 + quad * 4);
    f32x4 inv;
    #pragma unroll
    for (int r = 0; r < 4; r++) inv[r] = 1.f / lv[r];
    #pragma unroll
    for (int cb = 0; cb < 4; cb++) {
      #pragma unroll
      for (int r = 0; r < 4; r++) {
        float* p = ob + (size_t)(rb * 16 + quad * 4 + r) * D_ + cb * 16 + m;
        float v = acc[rb][cb][r];
        if (accumulate) v += *p;
        if (normalize) v *= inv[r];
        *p = v;
      }
    }
  }
}

extern "C" void kernel_launch(void* const* d_in, const int* in_sizes, int n_in,
                              void* d_out, int out_size, void* d_ws, size_t ws_size,
                              hipStream_t stream) {
  const float* x = (const float*)d_in[0];
  const float* U = (const float*)d_in[1];
  float* out = (float*)d_out;

  const size_t xt_b  = (size_t)B_ * D_ * T_ * 2;   // 16 MB
  const size_t ybf_b = (size_t)B_ * T_ * R_ * 2;   // 512 KB
  const size_t nsq_b = (size_t)B_ * T_ * 4;
  const size_t l_b   = nsq_b;
  const size_t base  = xt_b + ybf_b + nsq_b + l_b;
  const size_t pfull = (size_t)B_ * T_ * T_ * 2;   // 32 MB

  int nslab = 16;
  const int cand[5] = {1, 2, 4, 8, 16};
  for (int i = 0; i < 5; i++)
    if (base + pfull / (size_t)cand[i] <= ws_size) { nslab = cand[i]; break; }
  const int Kslab = T_ / nslab;

  unsigned short* xtp = (unsigned short*)d_ws;
  unsigned short* ybf = (unsigned short*)((char*)d_ws + xt_b);
  float* nsq = (float*)((char*)d_ws + xt_b + ybf_b);
  float* lp  = (float*)((char*)d_ws + xt_b + ybf_b + nsq_b);
  unsigned short* P = (unsigned short*)((char*)d_ws + base);

  hipLaunchKernelGGL(geo_y, dim3(B_ * T_ / 8), dim3(256), 0, stream, x, U, ybf, nsq, lp);
  hipLaunchKernelGGL(geo_xt, dim3(T_ / 64, D_ / 64, B_), dim3(256), 0, stream, x, xtp);
  for (int s = 0; s < nslab; s++) {
    hipLaunchKernelGGL(geo_scores, dim3(T_ / 128, Kslab / 128, B_), dim3(256), 0, stream,
                       ybf, nsq, P, lp, s * Kslab, Kslab);
    hipLaunchKernelGGL(geo_pv, dim3(128, 1, B_), dim3(256), 0, stream,
                       P, xtp, lp, out, Kslab, s * Kslab,
                       (int)(s > 0), (int)(s == nslab - 1));
  }
}

// Round 4
// 158.893 us; speedup vs baseline: 5.1698x; 1.3091x over previous
//
#include <hip/hip_runtime.h>

// GeodesicAttention: B=4, T=2048, D=1024, R=32
//   y = x @ U; logits[t,j] = 2 y_t.y_j - n_j  (row-const -n_t cancels)
//   KEY: max_j logit = n_t exactly (2ab - b^2 <= a^2, equality j=t), so
//   p[t,j] = exp(2 y_t.y_j - n_j - n_t) in (0,1] with NO online max/rescale.
// Pipeline (round 4: prep fused, y via MFMA — old geo_y was 77us of scalar
// U loads; geo_xt re-read all of x):
//   geo_ut   : Ut[r][d] = bf16(U[d][r])            (64 KB, L2-resident)
//   geo_prep : one pass over x: xt[b][d][t] = bf16(x), y = x@U via MFMA,
//              ybf = bf16(sqrt2*y), nsq = |y_bf|^2 (from rounded vals), l = 0
//   geo_scores : P[b][t][jloc] = bf16(exp(2yy - nj - nt)), l += rowsum
//   geo_pv     : out = (P @ xt^T) / l    (m97-style 128x128 bf16 GEMM)
#define B_ 4
#define T_ 2048
#define D_ 1024
#define R_ 32
#define XSTR 72   // prep LDS x-tile row stride in shorts (144B, 16B-aligned)

typedef __attribute__((ext_vector_type(8))) short short8;
typedef __attribute__((ext_vector_type(4))) float f32x4;
typedef __attribute__((ext_vector_type(4))) unsigned short us4;
typedef __attribute__((ext_vector_type(8))) unsigned short us8;

__device__ __forceinline__ unsigned short f2bf(float f) {
  union { float f; unsigned u; } v; v.f = f;
  unsigned r = (v.u + 0x7fffu + ((v.u >> 16) & 1u)) >> 16;
  return (unsigned short)r;
}
__device__ __forceinline__ float bf2f(unsigned short h) {
  union { unsigned u; float f; } v; v.u = (unsigned)h << 16;
  return v.f;
}

// ---------------- Ut[r][d] = bf16(U[d][r]) ----------------
__global__ __launch_bounds__(256)
void geo_ut(const float* __restrict__ U, unsigned short* __restrict__ Ut) {
  __shared__ float tile[128][33];
  const int tid = threadIdx.x;
  const int d0 = blockIdx.x * 128;
  #pragma unroll
  for (int i = 0; i < 16; i++) {
    int e = i * 256 + tid;            // 0..4095, coalesced
    int d = e >> 5, r = e & 31;
    tile[d][r] = U[(size_t)(d0 + d) * R_ + r];
  }
  __syncthreads();
  const int r = tid >> 3, seg = tid & 7;   // 32 r-rows x 8 segs of 16 d
  us8 o0, o1;
  #pragma unroll
  for (int k = 0; k < 8; k++) o0[k] = f2bf(tile[seg * 16 + k][r]);
  #pragma unroll
  for (int k = 0; k < 8; k++) o1[k] = f2bf(tile[seg * 16 + 8 + k][r]);
  *(us8*)(Ut + (size_t)r * D_ + d0 + seg * 16) = o0;
  *(us8*)(Ut + (size_t)r * D_ + d0 + seg * 16 + 8) = o1;
}

// ---------------- prep: xt + y(MFMA) + ybf + nsq + l, one pass over x -------
// grid (T/32, B), 4 waves. Per 64-d chunk: reg-double-buffered x loads ->
// bf16 LDS tile -> (a) us8 transposed xt stores, (b) wave w = (Mt,Nt) 16x16
// y C-tile, 2 MFMAs (K=64). C layout: row=t=quad*4+reg, col=r=lane&15.
__global__ __launch_bounds__(256)
void geo_prep(const float* __restrict__ x, const unsigned short* __restrict__ Ut,
              unsigned short* __restrict__ xt, unsigned short* __restrict__ ybf,
              float* __restrict__ nsq, float* __restrict__ l) {
  __shared__ unsigned short xs[32 * XSTR];   // 4.5 KB
  __shared__ float ys[32][33];               // 4.2 KB
  const int b = blockIdx.y;
  const int t0 = blockIdx.x * 32;
  const int tid = threadIdx.x, w = tid >> 6, lane = tid & 63;
  const int m = lane & 15, quad = lane >> 4;
  const int Mt = w & 1, Nt = w >> 1;
  const float* xb = x + ((size_t)b * T_ + t0) * D_;
  const int lr = tid >> 3;              // load: t-row 0..31
  const int lc = (tid & 7) * 8;         // load: 8 d per thread
  const int wd = tid >> 2;              // xt-write: d 0..63
  const int wt = (tid & 3) * 8;         // xt-write: 8 t per thread

  f32x4 acc = {0.f, 0.f, 0.f, 0.f};
  float4 r0 = *(const float4*)(xb + (size_t)lr * D_ + lc);
  float4 r1 = *(const float4*)(xb + (size_t)lr * D_ + lc + 4);

  for (int ch = 0; ch < 16; ch++) {
    const int d0 = ch * 64;
    us4 c0, c1;
    c0[0] = f2bf(r0.x); c0[1] = f2bf(r0.y); c0[2] = f2bf(r0.z); c0[3] = f2bf(r0.w);
    c1[0] = f2bf(r1.x); c1[1] = f2bf(r1.y); c1[2] = f2bf(r1.z); c1[3] = f2bf(r1.w);
    if (ch) __syncthreads();                 // prev chunk's consumers done
    *(us4*)(xs + lr * XSTR + lc) = c0;
    *(us4*)(xs + lr * XSTR + lc + 4) = c1;
    if (ch + 1 < 16) {                       // prefetch next chunk (hides HBM)
      r0 = *(const float4*)(xb + (size_t)lr * D_ + d0 + 64 + lc);
      r1 = *(const float4*)(xb + (size_t)lr * D_ + d0 + 64 + lc + 4);
    }
    __syncthreads();
    // transposed xt store: 8 t of one d per thread
    us8 o;
    #pragma unroll
    for (int k = 0; k < 8; k++) o[k] = xs[(wt + k) * XSTR + wd];
    *(us8*)(xt + ((size_t)b * D_ + d0 + wd) * T_ + t0 + wt) = o;
    // y MFMA: A = x-tile rows (t), B = Ut rows (r), K=64
    #pragma unroll
    for (int ks = 0; ks < 2; ks++) {
      short8 af = *(const short8*)(xs + (Mt * 16 + m) * XSTR + ks * 32 + quad * 8);
      short8 bf = *(const short8*)(Ut + (size_t)(Nt * 16 + m) * D_ + d0 + ks * 32 + quad * 8);
      acc = __builtin_amdgcn_mfma_f32_16x16x32_bf16(af, bf, acc, 0, 0, 0);
    }
  }
  #pragma unroll
  for (int r = 0; r < 4; r++)
    ys[Mt * 16 + quad * 4 + r][Nt * 16 + m] = acc[r];
  __syncthreads();
  {
    const int t = tid >> 3, rr = (tid & 7) * 4;
    us4 pk;
    #pragma unroll
    for (int r = 0; r < 4; r++) pk[r] = f2bf(1.41421356237f * ys[t][rr + r]);
    *(us4*)(ybf + ((size_t)b * T_ + t0 + t) * R_ + rr) = pk;
  }
  if (tid < 32) {
    float s = 0.f;
    #pragma unroll
    for (int r = 0; r < R_; r++) {
      float v = bf2f(f2bf(1.41421356237f * ys[tid][r]));  // what scores will see
      s += v * v;
    }
    nsq[(size_t)b * T_ + t0 + tid] = 0.5f * s;
    l[(size_t)b * T_ + t0 + tid] = 0.f;
  }
}

// ---------------- P[b][t][jloc] = bf16(exp(2yy - nj - nt)); l += rowsum -----
__global__ __launch_bounds__(256)
void geo_scores(const unsigned short* __restrict__ ybf,
                const float* __restrict__ nsq,
                unsigned short* __restrict__ P, float* __restrict__ l,
                int jg0, int Kslab) {
  const int b = blockIdx.z;
  const int t0 = blockIdx.x * 128;
  const int jl0 = blockIdx.y * 128;
  const int tid = threadIdx.x, w = tid >> 6, lane = tid & 63;
  const int m = lane & 15, quad = lane >> 4;
  const unsigned short* yb = ybf + (size_t)b * T_ * R_;
  const float* nb = nsq + b * T_;
  const int jw = jl0 + w * 32;
  short8 aj[2]; f32x4 njv[2];
  #pragma unroll
  for (int rb = 0; rb < 2; rb++) {
    aj[rb] = *(const short8*)(yb + (size_t)(jg0 + jw + rb * 16 + m) * R_ + quad * 8);
    njv[rb] = *(const f32x4*)(nb + jg0 + jw + rb * 16 + quad * 4);
  }
  unsigned short* Pb = P + (size_t)b * T_ * Kslab;
  #pragma unroll 2
  for (int cb = 0; cb < 8; cb++) {
    const int t = t0 + cb * 16 + m;
    short8 bt = *(const short8*)(yb + (size_t)t * R_ + quad * 8);
    float nt = nb[t];
    float ls = 0.f;
    #pragma unroll
    for (int rb = 0; rb < 2; rb++) {
      f32x4 z = {0.f, 0.f, 0.f, 0.f};
      f32x4 c = __builtin_amdgcn_mfma_f32_16x16x32_bf16(aj[rb], bt, z, 0, 0, 0);
      us4 pk;
      #pragma unroll
      for (int r = 0; r < 4; r++) {
        float p = __expf(c[r] - njv[rb][r] - nt);
        ls += p;
        pk[r] = f2bf(p);
      }
      *(us4*)(Pb + (size_t)t * Kslab + jw + rb * 16 + quad * 4) = pk;
    }
    ls += __shfl_xor(ls, 16, 64);
    ls += __shfl_xor(ls, 32, 64);
    if (quad == 0) atomicAdd(&l[b * T_ + t], ls);
  }
}

// ---------------- out = (P @ xt^T) / l  (m97-style 128x128, BK=64) ----------
__global__ __launch_bounds__(256)
void geo_pv(const unsigned short* __restrict__ P,
            const unsigned short* __restrict__ xt,
            const float* __restrict__ l, float* __restrict__ out,
            int Kslab, int kxt0, int accumulate, int normalize) {
  __shared__ unsigned short As[128 * 64];
  __shared__ unsigned short Bs[128 * 64];
  const int b = blockIdx.z;
  const int id = blockIdx.x;
  const int cls = id & 7, kk = id >> 3;
  const int t0 = (2 * cls + (kk >> 3)) * 128;
  const int d0 = (kk & 7) * 128;
  const int tid = threadIdx.x, w = tid >> 6, lane = tid & 63;
  const int m = lane & 15, quad = lane >> 4;
  const int wr = (w & 1) * 64, wc = (w >> 1) * 64;
  const int srow = lane >> 3, sslot = lane & 7;
  const unsigned short* Pb = P + ((size_t)b * T_ + t0) * Kslab;
  const unsigned short* Xb = xt + ((size_t)b * D_ + d0) * T_ + kxt0;
  f32x4 acc[4][4];
  #pragma unroll
  for (int i = 0; i < 4; i++)
    #pragma unroll
    for (int j = 0; j < 4; j++) acc[i][j] = (f32x4){0.f, 0.f, 0.f, 0.f};

  for (int k0 = 0; k0 < Kslab; k0 += 64) {
    __syncthreads();
    #pragma unroll
    for (int cc = 0; cc < 4; cc++) {
      const int row = w * 32 + cc * 8 + srow;
      const int gs = sslot ^ (row & 7);
      __builtin_amdgcn_global_load_lds(
          (const __attribute__((address_space(1))) void*)(Pb + (size_t)row * Kslab + k0 + gs * 8),
          (__attribute__((address_space(3))) void*)(As + (w * 32 + cc * 8) * 64),
          16, 0, 0);
      __builtin_amdgcn_global_load_lds(
          (const __attribute__((address_space(1))) void*)(Xb + (size_t)row * T_ + k0 + gs * 8),
          (__attribute__((address_space(3))) void*)(Bs + (w * 32 + cc * 8) * 64),
          16, 0, 0);
    }
    __syncthreads();
    #pragma unroll
    for (int ks = 0; ks < 2; ks++) {
      short8 af[4], bf[4];
      #pragma unroll
      for (int i = 0; i < 4; i++) {
        const int ra = wr + i * 16 + m;
        af[i] = *(const short8*)(As + ra * 64 + (((ks * 4 + quad) ^ (m & 7)) * 8));
        const int cd = wc + i * 16 + m;
        bf[i] = *(const short8*)(Bs + cd * 64 + (((ks * 4 + quad) ^ (m & 7)) * 8));
      }
      #pragma unroll
      for (int rb = 0; rb < 4; rb++)
        #pragma unroll
        for (int cb = 0; cb < 4; cb++)
          acc[rb][cb] = __builtin_amdgcn_mfma_f32_16x16x32_bf16(af[rb], bf[cb], acc[rb][cb], 0, 0, 0);
    }
  }
  float* ob = out + ((size_t)b * T_ + t0 + wr) * D_ + d0 + wc;
  #pragma unroll
  for (int rb = 0; rb < 4; rb++) {
    f32x4 lv = *(const f32x4*)(l + b * T_ + t0 + wr + rb * 16 + quad * 4);
    f32x4 inv;
    #pragma unroll
    for (int r = 0; r < 4; r++) inv[r] = 1.f / lv[r];
    #pragma unroll
    for (int cb = 0; cb < 4; cb++) {
      #pragma unroll
      for (int r = 0; r < 4; r++) {
        float* p = ob + (size_t)(rb * 16 + quad * 4 + r) * D_ + cb * 16 + m;
        float v = acc[rb][cb][r];
        if (accumulate) v += *p;
        if (normalize) v *= inv[r];
        *p = v;
      }
    }
  }
}

extern "C" void kernel_launch(void* const* d_in, const int* in_sizes, int n_in,
                              void* d_out, int out_size, void* d_ws, size_t ws_size,
                              hipStream_t stream) {
  const float* x = (const float*)d_in[0];
  const float* U = (const float*)d_in[1];
  float* out = (float*)d_out;

  const size_t xt_b  = (size_t)B_ * D_ * T_ * 2;   // 16 MB
  const size_t ybf_b = (size_t)B_ * T_ * R_ * 2;   // 512 KB
  const size_t nsq_b = (size_t)B_ * T_ * 4;
  const size_t l_b   = nsq_b;
  const size_t ut_b  = (size_t)D_ * R_ * 2;        // 64 KB
  const size_t base  = xt_b + ybf_b + nsq_b + l_b + ut_b;
  const size_t pfull = (size_t)B_ * T_ * T_ * 2;   // 32 MB

  int nslab = 16;
  const int cand[5] = {1, 2, 4, 8, 16};
  for (int i = 0; i < 5; i++)
    if (base + pfull / (size_t)cand[i] <= ws_size) { nslab = cand[i]; break; }
  const int Kslab = T_ / nslab;

  unsigned short* xtp = (unsigned short*)d_ws;
  unsigned short* ybf = (unsigned short*)((char*)d_ws + xt_b);
  float* nsq = (float*)((char*)d_ws + xt_b + ybf_b);
  float* lp  = (float*)((char*)d_ws + xt_b + ybf_b + nsq_b);
  unsigned short* Utp = (unsigned short*)((char*)d_ws + xt_b + ybf_b + nsq_b + l_b);
  unsigned short* P = (unsigned short*)((char*)d_ws + base);

  hipLaunchKernelGGL(geo_ut, dim3(D_ / 128), dim3(256), 0, stream, U, Utp);
  hipLaunchKernelGGL(geo_prep, dim3(T_ / 32, B_), dim3(256), 0, stream,
                     x, Utp, xtp, ybf, nsq, lp);
  for (int s = 0; s < nslab; s++) {
    hipLaunchKernelGGL(geo_scores, dim3(T_ / 128, Kslab / 128, B_), dim3(256), 0, stream,
                       ybf, nsq, P, lp, s * Kslab, Kslab);
    hipLaunchKernelGGL(geo_pv, dim3(128, 1, B_), dim3(256), 0, stream,
                       P, xtp, lp, out, Kslab, s * Kslab,
                       (int)(s > 0), (int)(s == nslab - 1));
  }
}

// Round 6
// 155.623 us; speedup vs baseline: 5.2784x; 1.0210x over previous
//
#include <hip/hip_runtime.h>

// GeodesicAttention: B=4, T=2048, D=1024, R=32
//   y = x @ U; logits[t,j] = 2 y_t.y_j - n_j  (row-const -n_t cancels)
//   KEY: max_j logit = n_t exactly (2ab - b^2 <= a^2, equality j=t), so
//   p[t,j] = exp(2 y_t.y_j - n_j - n_t) in (0,1] with NO online max/rescale.
// Round 6 = round 5 with the prep LDS stride bug fixed (XSTR2=136 >= 128-wide
// chunk; round 5 kept 72 and corrupted the tile).
//   geo_ut     : Ut[r][d] = bf16(U[d][r])
//   geo_prep   : xt[b][d][t] = bf16(x) for its d-slab, y_part[s] = x_slab @ U
//   geo_reduce : y = sum_s y_part, ybf = bf16(sqrt2*y), nsq = |ybf|^2, l = 0
//   geo_scores : P[b][t][jloc] = bf16(exp(2yy - nj - nt)), l += rowsum
//   geo_pv     : out = (P @ xt^T) / l    (m97-style 128x128 bf16 GEMM)
#define B_ 4
#define T_ 2048
#define D_ 1024
#define R_ 32
#define XSTR2 136  // prep LDS row stride in shorts (272B = 17*16B; row width 128)

typedef __attribute__((ext_vector_type(8))) short short8;
typedef __attribute__((ext_vector_type(4))) float f32x4;
typedef __attribute__((ext_vector_type(4))) unsigned short us4;
typedef __attribute__((ext_vector_type(8))) unsigned short us8;

__device__ __forceinline__ unsigned short f2bf(float f) {
  union { float f; unsigned u; } v; v.f = f;
  unsigned r = (v.u + 0x7fffu + ((v.u >> 16) & 1u)) >> 16;
  return (unsigned short)r;
}
__device__ __forceinline__ float bf2f(unsigned short h) {
  union { unsigned u; float f; } v; v.u = (unsigned)h << 16;
  return v.f;
}

// ---------------- Ut[r][d] = bf16(U[d][r]) ----------------
__global__ __launch_bounds__(256)
void geo_ut(const float* __restrict__ U, unsigned short* __restrict__ Ut) {
  __shared__ float tile[128][33];
  const int tid = threadIdx.x;
  const int d0 = blockIdx.x * 128;
  #pragma unroll
  for (int i = 0; i < 16; i++) {
    int e = i * 256 + tid;            // 0..4095, coalesced
    int d = e >> 5, r = e & 31;
    tile[d][r] = U[(size_t)(d0 + d) * R_ + r];
  }
  __syncthreads();
  const int r = tid >> 3, seg = tid & 7;   // 32 r-rows x 8 segs of 16 d
  us8 o0, o1;
  #pragma unroll
  for (int k = 0; k < 8; k++) o0[k] = f2bf(tile[seg * 16 + k][r]);
  #pragma unroll
  for (int k = 0; k < 8; k++) o1[k] = f2bf(tile[seg * 16 + 8 + k][r]);
  *(us8*)(Ut + (size_t)r * D_ + d0 + seg * 16) = o0;
  *(us8*)(Ut + (size_t)r * D_ + d0 + seg * 16 + 8) = o1;
}

// ---------------- prep: xt + partial y, one barrier, 4 blocks/CU ------------
// grid (T/32, B, 4 d-slabs). Block: 32 t x 256 d. Both 128-d chunks loaded to
// regs up-front (8 float4/thread), 2 LDS buffers, ONE __syncthreads, then
// transposed xt stores + 8 MFMAs (K=256) + coalesced y_part store.
__global__ __launch_bounds__(256)
void geo_prep(const float* __restrict__ x, const unsigned short* __restrict__ Ut,
              unsigned short* __restrict__ xt, float* __restrict__ y_part) {
  __shared__ unsigned short xs[2][32 * XSTR2];   // 2 x 8.7 KB
  const int b = blockIdx.y, slab = blockIdx.z;
  const int t0 = blockIdx.x * 32;
  const int d0 = slab * 256;
  const int tid = threadIdx.x, w = tid >> 6, lane = tid & 63;
  const int m = lane & 15, quad = lane >> 4;
  const int Mt = w & 1, Nt = w >> 1;
  const int lr = tid >> 3;              // load: t-row 0..31
  const int lc = (tid & 7) * 16;        // load: 16 d per thread per chunk

  const float* xb = x + ((size_t)b * T_ + t0 + lr) * D_ + d0 + lc;
  float4 v[2][4];
  #pragma unroll
  for (int ch = 0; ch < 2; ch++)
    #pragma unroll
    for (int i = 0; i < 4; i++)
      v[ch][i] = *(const float4*)(xb + ch * 128 + i * 4);
  #pragma unroll
  for (int ch = 0; ch < 2; ch++)
    #pragma unroll
    for (int i = 0; i < 4; i++) {
      us4 c;
      c[0] = f2bf(v[ch][i].x); c[1] = f2bf(v[ch][i].y);
      c[2] = f2bf(v[ch][i].z); c[3] = f2bf(v[ch][i].w);
      *(us4*)&xs[ch][lr * XSTR2 + lc + i * 4] = c;
    }
  __syncthreads();
  // transposed xt stores: per chunk, thread = (d-row 0..127, t-half), 2 us8
  {
    const int wd = tid >> 1, wt = (tid & 1) * 16;
    #pragma unroll
    for (int ch = 0; ch < 2; ch++) {
      us8 o0, o1;
      #pragma unroll
      for (int k = 0; k < 8; k++) {
        o0[k] = xs[ch][(wt + k) * XSTR2 + wd];
        o1[k] = xs[ch][(wt + 8 + k) * XSTR2 + wd];
      }
      unsigned short* xo = xt + ((size_t)b * D_ + d0 + ch * 128 + wd) * T_ + t0;
      *(us8*)(xo + wt) = o0;
      *(us8*)(xo + wt + 8) = o1;
    }
  }
  // partial y: A = x-tile rows (t), B = Ut rows (r), K = 256
  f32x4 acc = {0.f, 0.f, 0.f, 0.f};
  #pragma unroll
  for (int ch = 0; ch < 2; ch++)
    #pragma unroll
    for (int ks = 0; ks < 4; ks++) {
      short8 af = *(const short8*)&xs[ch][(Mt * 16 + m) * XSTR2 + ks * 32 + quad * 8];
      short8 bf = *(const short8*)(Ut + (size_t)(Nt * 16 + m) * D_ + d0 + ch * 128 + ks * 32 + quad * 8);
      acc = __builtin_amdgcn_mfma_f32_16x16x32_bf16(af, bf, acc, 0, 0, 0);
    }
  // C layout: row(t) = quad*4+reg, col(r) = m  -> 4 scalar stores
  float* yp = y_part + ((size_t)(slab * B_ + b) * T_ + t0 + Mt * 16 + quad * 4) * R_ + Nt * 16 + m;
  #pragma unroll
  for (int k = 0; k < 4; k++) yp[(size_t)k * R_] = acc[k];
}

// ---------------- reduce: y = sum_s y_part; ybf, nsq, l=0 -------------------
__global__ __launch_bounds__(256)
void geo_reduce(const float* __restrict__ y_part, unsigned short* __restrict__ ybf,
                float* __restrict__ nsq, float* __restrict__ l) {
  const int tid = threadIdx.x;
  const size_t row = (size_t)blockIdx.x * 32 + (tid >> 3);   // flat b*T+t
  const int r0 = (tid & 7) * 4;
  f32x4 v = {0.f, 0.f, 0.f, 0.f};
  #pragma unroll
  for (int s = 0; s < 4; s++) {
    f32x4 p = *(const f32x4*)(y_part + ((size_t)s * B_ * T_ + row) * R_ + r0);
    #pragma unroll
    for (int k = 0; k < 4; k++) v[k] += p[k];
  }
  us4 pk;
  float part = 0.f;
  #pragma unroll
  for (int k = 0; k < 4; k++) {
    pk[k] = f2bf(1.41421356237f * v[k]);
    float b = bf2f(pk[k]);             // exactly what scores will dot
    part += b * b;
  }
  *(us4*)(ybf + row * R_ + r0) = pk;
  part += __shfl_xor(part, 1, 64);
  part += __shfl_xor(part, 2, 64);
  part += __shfl_xor(part, 4, 64);
  if ((tid & 7) == 0) { nsq[row] = 0.5f * part; l[row] = 0.f; }
}

// ---------------- P[b][t][jloc] = bf16(exp(2yy - nj - nt)); l += rowsum -----
__global__ __launch_bounds__(256)
void geo_scores(const unsigned short* __restrict__ ybf,
                const float* __restrict__ nsq,
                unsigned short* __restrict__ P, float* __restrict__ l,
                int jg0, int Kslab) {
  const int b = blockIdx.z;
  const int t0 = blockIdx.x * 128;
  const int jl0 = blockIdx.y * 128;
  const int tid = threadIdx.x, w = tid >> 6, lane = tid & 63;
  const int m = lane & 15, quad = lane >> 4;
  const unsigned short* yb = ybf + (size_t)b * T_ * R_;
  const float* nb = nsq + b * T_;
  const int jw = jl0 + w * 32;
  short8 aj[2]; f32x4 njv[2];
  #pragma unroll
  for (int rb = 0; rb < 2; rb++) {
    aj[rb] = *(const short8*)(yb + (size_t)(jg0 + jw + rb * 16 + m) * R_ + quad * 8);
    njv[rb] = *(const f32x4*)(nb + jg0 + jw + rb * 16 + quad * 4);
  }
  unsigned short* Pb = P + (size_t)b * T_ * Kslab;
  short8 btn = *(const short8*)(yb + (size_t)(t0 + m) * R_ + quad * 8);
  float ntn = nb[t0 + m];
  #pragma unroll 2
  for (int cb = 0; cb < 8; cb++) {
    const int t = t0 + cb * 16 + m;
    short8 bt = btn;
    float nt = ntn;
    if (cb < 7) {
      btn = *(const short8*)(yb + (size_t)(t + 16) * R_ + quad * 8);
      ntn = nb[t + 16];
    }
    float ls = 0.f;
    #pragma unroll
    for (int rb = 0; rb < 2; rb++) {
      f32x4 z = {0.f, 0.f, 0.f, 0.f};
      f32x4 c = __builtin_amdgcn_mfma_f32_16x16x32_bf16(aj[rb], bt, z, 0, 0, 0);
      us4 pk;
      #pragma unroll
      for (int r = 0; r < 4; r++) {
        float p = __expf(c[r] - njv[rb][r] - nt);
        ls += p;
        pk[r] = f2bf(p);
      }
      *(us4*)(Pb + (size_t)t * Kslab + jw + rb * 16 + quad * 4) = pk;
    }
    ls += __shfl_xor(ls, 16, 64);
    ls += __shfl_xor(ls, 32, 64);
    if (quad == 0) atomicAdd(&l[b * T_ + t], ls);
  }
}

// ---------------- out = (P @ xt^T) / l  (m97-style 128x128, BK=64) ----------
__global__ __launch_bounds__(256)
void geo_pv(const unsigned short* __restrict__ P,
            const unsigned short* __restrict__ xt,
            const float* __restrict__ l, float* __restrict__ out,
            int Kslab, int kxt0, int accumulate, int normalize) {
  __shared__ unsigned short As[128 * 64];
  __shared__ unsigned short Bs[128 * 64];
  const int b = blockIdx.z;
  const int id = blockIdx.x;
  const int cls = id & 7, kk = id >> 3;
  const int t0 = (2 * cls + (kk >> 3)) * 128;
  const int d0 = (kk & 7) * 128;
  const int tid = threadIdx.x, w = tid >> 6, lane = tid & 63;
  const int m = lane & 15, quad = lane >> 4;
  const int wr = (w & 1) * 64, wc = (w >> 1) * 64;
  const int srow = lane >> 3, sslot = lane & 7;
  const unsigned short* Pb = P + ((size_t)b * T_ + t0) * Kslab;
  const unsigned short* Xb = xt + ((size_t)b * D_ + d0) * T_ + kxt0;
  f32x4 acc[4][4];
  #pragma unroll
  for (int i = 0; i < 4; i++)
    #pragma unroll
    for (int j = 0; j < 4; j++) acc[i][j] = (f32x4){0.f, 0.f, 0.f, 0.f};

  for (int k0 = 0; k0 < Kslab; k0 += 64) {
    __syncthreads();
    #pragma unroll
    for (int cc = 0; cc < 4; cc++) {
      const int row = w * 32 + cc * 8 + srow;
      const int gs = sslot ^ (row & 7);
      __builtin_amdgcn_global_load_lds(
          (const __attribute__((address_space(1))) void*)(Pb + (size_t)row * Kslab + k0 + gs * 8),
          (__attribute__((address_space(3))) void*)(As + (w * 32 + cc * 8) * 64),
          16, 0, 0);
      __builtin_amdgcn_global_load_lds(
          (const __attribute__((address_space(1))) void*)(Xb + (size_t)row * T_ + k0 + gs * 8),
          (__attribute__((address_space(3))) void*)(Bs + (w * 32 + cc * 8) * 64),
          16, 0, 0);
    }
    __syncthreads();
    #pragma unroll
    for (int ks = 0; ks < 2; ks++) {
      short8 af[4], bf[4];
      #pragma unroll
      for (int i = 0; i < 4; i++) {
        const int ra = wr + i * 16 + m;
        af[i] = *(const short8*)(As + ra * 64 + (((ks * 4 + quad) ^ (m & 7)) * 8));
        const int cd = wc + i * 16 + m;
        bf[i] = *(const short8*)(Bs + cd * 64 + (((ks * 4 + quad) ^ (m & 7)) * 8));
      }
      #pragma unroll
      for (int rb = 0; rb < 4; rb++)
        #pragma unroll
        for (int cb = 0; cb < 4; cb++)
          acc[rb][cb] = __builtin_amdgcn_mfma_f32_16x16x32_bf16(af[rb], bf[cb], acc[rb][cb], 0, 0, 0);
    }
  }
  float* ob = out + ((size_t)b * T_ + t0 + wr) * D_ + d0 + wc;
  #pragma unroll
  for (int rb = 0; rb < 4; rb++) {
    f32x4 lv = *(const f32x4*)(l + b * T_ + t0 + wr + rb * 16 + quad * 4);
    f32x4 inv;
    #pragma unroll
    for (int r = 0; r < 4; r++) inv[r] = 1.f / lv[r];
    #pragma unroll
    for (int cb = 0; cb < 4; cb++) {
      #pragma unroll
      for (int r = 0; r < 4; r++) {
        float* p = ob + (size_t)(rb * 16 + quad * 4 + r) * D_ + cb * 16 + m;
        float v = acc[rb][cb][r];
        if (accumulate) v += *p;
        if (normalize) v *= inv[r];
        *p = v;
      }
    }
  }
}

extern "C" void kernel_launch(void* const* d_in, const int* in_sizes, int n_in,
                              void* d_out, int out_size, void* d_ws, size_t ws_size,
                              hipStream_t stream) {
  const float* x = (const float*)d_in[0];
  const float* U = (const float*)d_in[1];
  float* out = (float*)d_out;

  const size_t xt_b  = (size_t)B_ * D_ * T_ * 2;   // 16 MB
  const size_t ybf_b = (size_t)B_ * T_ * R_ * 2;   // 512 KB
  const size_t nsq_b = (size_t)B_ * T_ * 4;
  const size_t l_b   = nsq_b;
  const size_t ut_b  = (size_t)D_ * R_ * 2;        // 64 KB
  const size_t yp_b  = (size_t)4 * B_ * T_ * R_ * 4;  // 4 MB partial y
  const size_t base  = xt_b + ybf_b + nsq_b + l_b + ut_b + yp_b;
  const size_t pfull = (size_t)B_ * T_ * T_ * 2;   // 32 MB

  int nslab = 16;
  const int cand[5] = {1, 2, 4, 8, 16};
  for (int i = 0; i < 5; i++)
    if (base + pfull / (size_t)cand[i] <= ws_size) { nslab = cand[i]; break; }
  const int Kslab = T_ / nslab;

  char* wp = (char*)d_ws;
  unsigned short* xtp = (unsigned short*)wp;                 wp += xt_b;
  unsigned short* ybf = (unsigned short*)wp;                 wp += ybf_b;
  float* nsq = (float*)wp;                                   wp += nsq_b;
  float* lp  = (float*)wp;                                   wp += l_b;
  unsigned short* Utp = (unsigned short*)wp;                 wp += ut_b;
  float* ypart = (float*)wp;                                 wp += yp_b;
  unsigned short* P = (unsigned short*)wp;

  hipLaunchKernelGGL(geo_ut, dim3(D_ / 128), dim3(256), 0, stream, U, Utp);
  hipLaunchKernelGGL(geo_prep, dim3(T_ / 32, B_, 4), dim3(256), 0, stream,
                     x, Utp, xtp, ypart);
  hipLaunchKernelGGL(geo_reduce, dim3(B_ * T_ / 32), dim3(256), 0, stream,
                     ypart, ybf, nsq, lp);
  for (int s = 0; s < nslab; s++) {
    hipLaunchKernelGGL(geo_scores, dim3(T_ / 128, Kslab / 128, B_), dim3(256), 0, stream,
                       ybf, nsq, P, lp, s * Kslab, Kslab);
    hipLaunchKernelGGL(geo_pv, dim3(128, 1, B_), dim3(256), 0, stream,
                       P, xtp, lp, out, Kslab, s * Kslab,
                       (int)(s > 0), (int)(s == nslab - 1));
  }
}